// Round 14
// baseline (137.225 us; speedup 1.0000x reference)
//
#include <hip/hip_runtime.h>
#include <math.h>
#include <stdint.h>

#define BB   4
#define NN   1024
#define HID  768
#define NH   12
#define DH   64
#define NREL 64
#define EE   65536
#define NSEG (BB*NN)   /* 4096 */
#define NOUT 4608      /* 6*HID stacked output features */
#define UNIT_E 32      /* edges per logits block */
#define MAXU (EE/UNIT_E + NREL)
#define NBLK 256       /* blocks in relation radix sort */
#define MAXMT 34       /* max M-tiles in partitioned GEMM */

typedef __bf16 bf16;
typedef __bf16 bf16x8 __attribute__((ext_vector_type(8)));
typedef float  f32x4  __attribute__((ext_vector_type(4)));

__device__ __forceinline__ void load_lds16(const void* g, void* l) {
  __builtin_amdgcn_global_load_lds(
      (__attribute__((address_space(1))) void*)(uintptr_t)g,
      (__attribute__((address_space(3))) void*)(uintptr_t)l, 16, 0, 0);
}

// LDS XOR swizzle (involution, moves 16B slots within each 128B window)
__device__ __forceinline__ int swz(int byte_off) {
  return byte_off ^ (((byte_off >> 7) & 7) << 4);
}

__device__ __forceinline__ float b2f(unsigned short u) {
  return __uint_as_float(((unsigned)u) << 16);
}

// ---------------- P0: partition rows by node type; zero cnt ----------------
__global__ __launch_bounds__(1024)
void partition_kernel(const int* __restrict__ nt, int* __restrict__ origrow,
                      int* __restrict__ meta, int* __restrict__ cnt){
  __shared__ int sums[1024];
  __shared__ int ntot;
  const int t = threadIdx.x;
  int tk[4]; int c = 0;
  #pragma unroll
  for (int i=0;i<4;i++){ tk[i] = (nt[t*4+i]==0); c += tk[i]; cnt[t*4+i] = 0; }
  sums[t]=c; __syncthreads();
  for (int off=1; off<1024; off<<=1){
    const int v = (t>=off) ? sums[t-off] : 0;
    __syncthreads();
    sums[t]+=v;
    __syncthreads();
  }
  if (t==1023) ntot = sums[1023];
  __syncthreads();
  const int excl = sums[t]-c;
  int tokpos = excl, kbpos = ntot + (4*t - excl);
  #pragma unroll
  for (int i=0;i<4;i++){
    if (tk[i]) origrow[tokpos++] = t*4+i;
    else       origrow[kbpos++]  = t*4+i;
  }
  if (t==0){
    const int ntok = ntot, nkb = NSEG - ntok;
    const int tt = (ntok+127)>>7, ktt = (nkb+127)>>7;
    meta[0]=ntok; meta[1]=tt+ktt;
    for (int m=0;m<tt+ktt;m++){
      meta[2+m]  = (m<tt) ? m*128 : ntok + (m-tt)*128;
      meta[40+m] = (m<tt) ? 1 : 0;
    }
  }
}

// ---------------- P1: fused converts (X-gather, W stack, M^T, emb) + histograms ----
__global__ __launch_bounds__(256)
void prep_kernel(const float* __restrict__ X, const int* __restrict__ origrow,
                 const float* __restrict__ W0, const float* __restrict__ W1,
                 const float* __restrict__ W2, const float* __restrict__ W3,
                 const float* __restrict__ W4, const float* __restrict__ W5,
                 const float* __restrict__ b0, const float* __restrict__ b1,
                 const float* __restrict__ b2, const float* __restrict__ b3,
                 const float* __restrict__ b4, const float* __restrict__ b5,
                 const float* __restrict__ relm, const float* __restrict__ emb,
                 const int* __restrict__ ei,
                 bf16* __restrict__ Xp, bf16* __restrict__ Wb,
                 float* __restrict__ biasAll, bf16* __restrict__ Mt,
                 bf16* __restrict__ Eb, int* __restrict__ cnt,
                 int* __restrict__ cnt_blk){
  __shared__ int lc[NREL];
  const int blk = blockIdx.x, tid = threadIdx.x;
  if (blk < NSEG) {
    if (tid < 192) {
      const int orig = origrow[blk];
      float4 v = *reinterpret_cast<const float4*>(X + (size_t)orig*HID + tid*4);
      bf16 o[4] = {(bf16)v.x,(bf16)v.y,(bf16)v.z,(bf16)v.w};
      *reinterpret_cast<uint64_t*>(Xp + (size_t)blk*HID + tid*4) = *reinterpret_cast<uint64_t*>(o);
    }
  } else if (blk < NSEG + NOUT) {
    const int r = blk - NSEG;
    const int j = r / HID;
    const int o = r - j * HID;
    const float* Wj; const float* bj;
    if      (j==0){Wj=W0;bj=b0;} else if(j==1){Wj=W1;bj=b1;}
    else if (j==2){Wj=W2;bj=b2;} else if(j==3){Wj=W3;bj=b3;}
    else if (j==4){Wj=W4;bj=b4;} else            {Wj=W5;bj=b5;}
    if (tid < 192) {
      float4 v = *reinterpret_cast<const float4*>(Wj + (size_t)o*HID + tid*4);
      bf16 ob[4] = {(bf16)v.x,(bf16)v.y,(bf16)v.z,(bf16)v.w};
      *reinterpret_cast<uint64_t*>(Wb + (size_t)r*HID + tid*4) = *reinterpret_cast<uint64_t*>(ob);
    }
    if (tid == 0) biasAll[r] = bj[o];
  } else if (blk < NSEG + NOUT + NREL) {
    const int r = blk - NSEG - NOUT;
    const float* M = relm + (size_t)r * DH * DH;
    bf16* o = Mt + (size_t)r * DH * DH;
    for (int i = tid; i < DH * DH; i += 256) {
      const int d = i >> 6, f = i & 63;
      o[f * DH + d] = (bf16)M[i];
    }
  } else if (blk < NSEG + NOUT + 2*NREL) {
    const int r = blk - NSEG - NOUT - NREL;
    const float* src = emb + (size_t)r * HID;
    bf16* dst = Eb + (size_t)r * HID;
    for (int c = tid; c < HID; c += 256) dst[c] = (bf16)src[c];
  } else {
    // fused histograms: seg (global atomics) + rel (LDS -> cnt_blk)
    const int blk2 = blk - (NSEG + NOUT + 2*NREL);
    if (tid < NREL) lc[tid] = 0;
    __syncthreads();
    const int e = blk2*256 + tid;
    atomicAdd(&cnt[ei[e]*NN + ei[EE+e]], 1);
    atomicAdd(&lc[ei[3*EE+e]], 1);
    __syncthreads();
    if (tid < NREL) cnt_blk[tid*NBLK + blk2] = lc[tid];
  }
}

// ---------------- K1: type-partitioned bf16 MFMA GEMM, 128x128 tile ----------------
// 3-buffer LDS pipeline, counted vmcnt, one raw barrier/iter, XCD-chunked m-major grid.
#define BM 128
#define BN 128
#define BK 32
#define NT (HID/BK)   /* 24 K-iterations */
#define NCT 18        /* 2304/BN col tiles */
#define NWG (MAXMT*NCT) /* 612 */

__global__ __launch_bounds__(256)
void gemm_kernel(const bf16* __restrict__ A, const bf16* __restrict__ Bw,
                 const float* __restrict__ biasAll, const int* __restrict__ origrow,
                 const int* __restrict__ meta,
                 bf16* __restrict__ Qb, bf16* __restrict__ Kb, bf16* __restrict__ Vb)
{
  __shared__ bf16 As[3][BM * BK];   // 3 x 8 KB
  __shared__ bf16 Bs[3][BN * BK];   // 3 x 8 KB

  // m204 bijective XCD chunking: q=612/8=76, r=612%8=4
  const int orig = blockIdx.x;
  const int xcd  = orig & 7;
  const int wg   = (xcd < 4 ? xcd * 77 : 4 * 77 + (xcd - 4) * 76) + (orig >> 3);
  const int mt   = wg / NCT;        // m-major: consecutive wg share mt (A-local per XCD)
  const int ctt  = wg - mt * NCT;

  const int ntok = meta[0], nmt = meta[1];
  if (mt >= nmt) return;
  const int base  = meta[2+mt];
  const int istok = meta[40+mt];

  const int tid  = threadIdx.x;
  const int lane = tid & 63;
  const int w    = tid >> 6;
  const int wrow = w >> 1, wcol = w & 1;   // 2x2 waves; wave tile 64x64
  const int ct_local = ctt * BN;           // 0..2176
  const int brow0 = (istok ? 0 : 2304) + ct_local;

  f32x4 acc[4][4];
  #pragma unroll
  for (int mi=0;mi<4;mi++)
    #pragma unroll
    for (int ni=0;ni<4;ni++) acc[mi][ni] = (f32x4){0.f,0.f,0.f,0.f};

  const char* Ab = (const char*)A;
  const char* Bb = (const char*)Bw;

  int rowg[2], inrowg[2], Pg[2];
  #pragma unroll
  for (int i = 0; i < 2; ++i) {
    const int P = (i * 256 + tid) * 16;
    const int L = swz(P);
    Pg[i] = P; rowg[i] = L >> 6; inrowg[i] = L & 63;
  }

  #define STAGE(kt, b)                                                              \
    { _Pragma("unroll")                                                             \
      for (int i = 0; i < 2; ++i) {                                                 \
        load_lds16(Ab + ((size_t)(base  + rowg[i]) * HID + (kt) * BK) * 2 + inrowg[i], \
                   (char*)As[b] + Pg[i]);                                           \
        load_lds16(Bb + ((size_t)(brow0 + rowg[i]) * HID + (kt) * BK) * 2 + inrowg[i], \
                   (char*)Bs[b] + Pg[i]);                                           \
      } }

  STAGE(0, 0);
  STAGE(1, 1);

  for (int kt = 0; kt < NT; ++kt) {
    if (kt < NT - 1) asm volatile("s_waitcnt vmcnt(4)" ::: "memory");
    else             asm volatile("s_waitcnt vmcnt(0)" ::: "memory");
    __builtin_amdgcn_s_barrier();
    if (kt + 2 < NT) { STAGE(kt + 2, (kt + 2) % 3); }

    const char* Asb = (const char*)As[kt % 3];
    const char* Bsb = (const char*)Bs[kt % 3];
    bf16x8 af[4], bfr[4];
    #pragma unroll
    for (int mi = 0; mi < 4; ++mi) {
      const int r = wrow * 64 + mi * 16 + (lane & 15);
      const int L = r * 64 + (lane >> 4) * 16;
      af[mi] = *reinterpret_cast<const bf16x8*>(Asb + swz(L));
    }
    #pragma unroll
    for (int ni = 0; ni < 4; ++ni) {
      const int r = wcol * 64 + ni * 16 + (lane & 15);
      const int L = r * 64 + (lane >> 4) * 16;
      bfr[ni] = *reinterpret_cast<const bf16x8*>(Bsb + swz(L));
    }
    #pragma unroll
    for (int mi = 0; mi < 4; ++mi)
      #pragma unroll
      for (int ni = 0; ni < 4; ++ni)
        acc[mi][ni] = __builtin_amdgcn_mfma_f32_16x16x32_bf16(af[mi], bfr[ni], acc[mi][ni], 0, 0, 0);
  }

  const int j3 = ct_local / HID;
  const int o0 = ct_local - j3 * HID;
  const int rowLim = istok ? ntok : NSEG;
  const int bidx0 = (istok ? j3 : j3 + 3) * HID + o0;
  #pragma unroll
  for (int mi = 0; mi < 4; ++mi) {
    #pragma unroll
    for (int i = 0; i < 4; ++i) {
      const int rr = base + wrow * 64 + mi * 16 + (lane >> 4) * 4 + i;
      if (rr < rowLim) {
        const int orig2 = origrow[rr];
        #pragma unroll
        for (int ni = 0; ni < 4; ++ni) {
          const int cg = wcol * 64 + ni * 16 + (lane & 15);
          const float val = acc[mi][ni][i] + biasAll[bidx0 + cg];
          if (j3 == 2)      Vb[(size_t)orig2 * HID + o0 + cg] = (bf16)val;
          else if (j3 == 0) Qb[(size_t)orig2 * HID + o0 + cg] = (bf16)val;
          else              Kb[(size_t)orig2 * HID + o0 + cg] = (bf16)val;
        }
      }
    }
  }
}

// ---------------- fused scans ----------------
__global__ __launch_bounds__(1024)
void scan_both_kernel(const int* __restrict__ cnt, int* __restrict__ start,
                      int* __restrict__ cursor, int* __restrict__ cnt_blk,
                      int* __restrict__ start_rel, int* __restrict__ cnt_rel,
                      int* __restrict__ ustart){
  __shared__ int sums[1024];
  const int t = threadIdx.x;
  if (blockIdx.x == 0) {
    const int c0=cnt[t*4], c1=cnt[t*4+1], c2=cnt[t*4+2], c3=cnt[t*4+3];
    const int s = c0+c1+c2+c3;
    sums[t]=s; __syncthreads();
    for (int off=1; off<1024; off<<=1){
      const int v = (t>=off) ? sums[t-off] : 0;
      __syncthreads();
      sums[t]+=v;
      __syncthreads();
    }
    const int excl = sums[t]-s;
    const int o0=excl, o1=o0+c0, o2=o1+c1, o3=o2+c2;
    start[t*4]=o0;  start[t*4+1]=o1;  start[t*4+2]=o2;  start[t*4+3]=o3;
    cursor[t*4]=o0; cursor[t*4+1]=o1; cursor[t*4+2]=o2; cursor[t*4+3]=o3;
  } else {
    int v[16]; int s = 0;
    #pragma unroll
    for (int i=0;i<16;i++){ v[i] = cnt_blk[t*16+i]; s += v[i]; }
    sums[t] = s; __syncthreads();
    for (int off=1; off<1024; off<<=1){
      const int x = (t>=off) ? sums[t-off] : 0;
      __syncthreads();
      sums[t] += x;
      __syncthreads();
    }
    int run = sums[t] - s;
    #pragma unroll
    for (int i=0;i<16;i++){ const int c = v[i]; cnt_blk[t*16+i] = run; run += c; }
    __syncthreads();
    if (t < NREL) {
      const int st  = cnt_blk[t*NBLK];
      const int nxt = (t == NREL-1) ? EE : cnt_blk[(t+1)*NBLK];
      const int c   = nxt - st;
      start_rel[t] = st;
      cnt_rel[t]   = c;
      const int units = (c + UNIT_E - 1) / UNIT_E;
      int su = units;
      #pragma unroll
      for (int off=1; off<64; off<<=1) {
        const int vu = __shfl_up(su, off);
        if (t >= off) su += vu;
      }
      ustart[t] = su - units;
      if (t == NREL-1) ustart[NREL] = su;
    }
  }
}

// ---------------- fused scatters ----------------
__global__ __launch_bounds__(256)
void scatter_both_kernel(const int* __restrict__ ei, int* __restrict__ cursor,
                         int* __restrict__ order, const int* __restrict__ base_blk,
                         int* __restrict__ order_rel){
  __shared__ int lc[NREL];
  const int tid = threadIdx.x, blk = blockIdx.x;
  if (tid < NREL) lc[tid] = 0;
  __syncthreads();
  const int e = blk*256 + tid;
  const int seg = ei[e]*NN + ei[EE+e];
  order[atomicAdd(&cursor[seg], 1)] = e;
  const int r = ei[3*EE + e];
  const int rank = atomicAdd(&lc[r], 1);
  order_rel[base_blk[r*NBLK + blk] + rank] = e;
}

// ---------------- K2: relation-batched MFMA logits, 32 edges/block, pipelined ----
// wave handles 8 edges = 96 (edge,head) rows = 6 tiles of 16
__global__ __launch_bounds__(256)
void logits_mfma_kernel(const bf16* __restrict__ Qb, const bf16* __restrict__ Kb,
                        const int* __restrict__ ei, const bf16* __restrict__ Mt,
                        const int* __restrict__ order_rel, const int* __restrict__ start_rel,
                        const int* __restrict__ cnt_rel, const int* __restrict__ ustart,
                        float* __restrict__ L)
{
  __shared__ int qoff[UNIT_E], koff[UNIT_E], eidx[UNIT_E];
  __shared__ int us[NREL+1];
  __shared__ int relsh;
  const int tid = threadIdx.x;
  const int u = blockIdx.x;
  if (tid < NREL+1) us[tid] = ustart[tid];
  __syncthreads();
  if (u >= us[NREL]) return;
  if (tid < NREL && us[tid] <= u && u < us[tid+1]) relsh = tid;
  __syncthreads();
  const int r = relsh;
  const int lu = u - us[r];
  const int ebase = start_rel[r] + lu * UNIT_E;
  const int nvalid = min(UNIT_E, cnt_rel[r] - lu * UNIT_E);
  if (tid < UNIT_E) {
    const int epos = ebase + (tid < nvalid ? tid : 0);
    const int e = order_rel[epos];
    eidx[tid] = (tid < nvalid) ? e : -1;
    const int eb = ei[e], eh = ei[EE+e], et = ei[2*EE+e];
    qoff[tid] = (eb*NN + eh) * HID;
    koff[tid] = (eb*NN + et) * HID;
  }
  __syncthreads();

  const int w = tid >> 6, lane = tid & 63;
  const int l15 = lane & 15, lg = lane >> 4;
  const bf16* Mr = Mt + (size_t)r * DH * DH;
  bf16x8 bfr[4][2];
  #pragma unroll
  for (int ni = 0; ni < 4; ++ni)
    #pragma unroll
    for (int kk = 0; kk < 2; ++kk)
      bfr[ni][kk] = *reinterpret_cast<const bf16x8*>(
          Mr + (ni*16 + l15) * DH + kk*32 + lg*8);

  #define LOADQ(mt, a0, a1)                                              \
    { const int lr = (mt)*16 + l15;                                      \
      const int el = lr / 12, hh = lr - el*12;                           \
      const int qo = qoff[w*8 + el] + hh*64 + lg*8;                      \
      a0 = *reinterpret_cast<const bf16x8*>(Qb + qo);                    \
      a1 = *reinterpret_cast<const bf16x8*>(Qb + qo + 32); }

  #define LOADK(mt, kr)                                                  \
    { _Pragma("unroll")                                                  \
      for (int i = 0; i < 4; ++i) {                                      \
        const int lr2 = (mt)*16 + lg*4 + i;                              \
        const int el2 = lr2 / 12, h2 = lr2 - el2*12;                     \
        const int ko = koff[w*8 + el2] + h2*64 + l15;                    \
        _Pragma("unroll")                                                \
        for (int ni = 0; ni < 4; ++ni)                                   \
          kr[i*4+ni] = *reinterpret_cast<const unsigned short*>(Kb + ko + ni*16); } }

  #define COMPUTE(mt, a0, a1, kr)                                        \
    { f32x4 acc_[4];                                                     \
      _Pragma("unroll")                                                  \
      for (int ni = 0; ni < 4; ++ni) {                                   \
        acc_[ni] = (f32x4){0.f,0.f,0.f,0.f};                             \
        acc_[ni] = __builtin_amdgcn_mfma_f32_16x16x32_bf16(a0, bfr[ni][0], acc_[ni], 0, 0, 0); \
        acc_[ni] = __builtin_amdgcn_mfma_f32_16x16x32_bf16(a1, bfr[ni][1], acc_[ni], 0, 0, 0); \
      }                                                                  \
      _Pragma("unroll")                                                  \
      for (int i = 0; i < 4; ++i) {                                      \
        const int lr2 = (mt)*16 + lg*4 + i;                              \
        const int el2 = lr2 / 12, h2 = lr2 - el2*12;                     \
        float p = acc_[0][i]*b2f(kr[i*4+0]) + acc_[1][i]*b2f(kr[i*4+1])  \
                + acc_[2][i]*b2f(kr[i*4+2]) + acc_[3][i]*b2f(kr[i*4+3]); \
        p += __shfl_xor(p, 1); p += __shfl_xor(p, 2);                    \
        p += __shfl_xor(p, 4); p += __shfl_xor(p, 8);                    \
        if (l15 == 0) {                                                  \
          const int e = eidx[w*8 + el2];                                 \
          if (e >= 0) L[(size_t)e*NH + h2] = p * 0.125f;                 \
        } } }

  bf16x8 a0A, a1A, a0B, a1B;
  unsigned short krA[16], krB[16];
  LOADQ(0, a0A, a1A); LOADK(0, krA);
  #pragma unroll
  for (int mt = 0; mt < 6; mt += 2) {
    LOADQ(mt+1, a0B, a1B); LOADK(mt+1, krB);
    COMPUTE(mt, a0A, a1A, krA);
    if (mt + 2 < 6) { LOADQ(mt+2, a0A, a1A); LOADK(mt+2, krA); }
    COMPUTE(mt+1, a0B, a1B, krB);
  }
  #undef LOADQ
  #undef LOADK
  #undef COMPUTE
}

// ---------------- K4: per-segment softmax + weighted V scatter-sum ----------------
#define SEGCAP 128
__global__ __launch_bounds__(256)
void segout_kernel(const int* __restrict__ ei, const bf16* __restrict__ Vb,
                   const bf16* __restrict__ Eb, const float* __restrict__ L,
                   const int* __restrict__ start, const int* __restrict__ cnt,
                   const int* __restrict__ order, float* __restrict__ out)
{
  const int s = blockIdx.x, tid = threadIdx.x;
  float* o = out + (size_t)s*HID;
  const int n = cnt[s];
  if (n==0){ o[tid]=0.f; o[tid+256]=0.f; o[tid+512]=0.f; return; }

  __shared__ float denom[NH];
  __shared__ float inv[NH];
  const int st = start[s];
  const int eb = s >> 10;
  const int h0 = tid >> 6;

  if (tid<NH) denom[tid]=0.f;

  if (n <= SEGCAP) {
    __shared__ float pr[SEGCAP*NH];
    __shared__ int voffs[SEGCAP];
    __shared__ int eoffs[SEGCAP];
    if (tid < n) {
      const int e = order[st + tid];
      voffs[tid] = (eb*NN + ei[2*EE+e]) * HID;
      eoffs[tid] = ei[3*EE+e] * HID;
    }
    __syncthreads();
    for (int idx=tid; idx<n*NH; idx+=256){
      const int e = order[st + idx/NH];
      const float v = expf(L[(size_t)e*NH + idx - (idx/NH)*NH]);
      pr[idx] = v;
      atomicAdd(&denom[idx - (idx/NH)*NH], v);
    }
    __syncthreads();
    if (tid<NH) inv[tid] = 1.f/denom[tid];
    __syncthreads();
    const float i0=inv[h0], i1=inv[h0+4], i2=inv[h0+8];
    float a0=0.f, a1=0.f, a2=0.f;
    float b0_=0.f, b1_=0.f, b2_=0.f;
    #define EDGE_ACC(ii, A0, A1, A2)                                                     \
      { const bf16* vr = Vb + voffs[ii];                                                 \
        const bf16* er = Eb + eoffs[ii];                                                 \
        const float p0 = pr[(ii)*NH+h0  ]*i0;                                            \
        const float p1 = pr[(ii)*NH+h0+4]*i1;                                            \
        const float p2 = pr[(ii)*NH+h0+8]*i2;                                            \
        A0 += p0*(b2f(*(const unsigned short*)(vr+tid    ))+b2f(*(const unsigned short*)(er+tid    ))); \
        A1 += p1*(b2f(*(const unsigned short*)(vr+tid+256))+b2f(*(const unsigned short*)(er+tid+256))); \
        A2 += p2*(b2f(*(const unsigned short*)(vr+tid+512))+b2f(*(const unsigned short*)(er+tid+512))); }
    int i = 0;
    for (; i+3<n; i+=4){
      EDGE_ACC(i,   a0,  a1,  a2);
      EDGE_ACC(i+1, b0_, b1_, b2_);
      EDGE_ACC(i+2, a0,  a1,  a2);
      EDGE_ACC(i+3, b0_, b1_, b2_);
    }
    for (; i<n; ++i){
      EDGE_ACC(i, a0, a1, a2);
    }
    #undef EDGE_ACC
    o[tid]=a0+b0_; o[tid+256]=a1+b1_; o[tid+512]=a2+b2_;
  } else {
    __syncthreads();
    for (int i=tid; i<n*NH; i+=256){
      const int e = order[st + i/NH];
      atomicAdd(&denom[i - (i/NH)*NH], expf(L[(size_t)e*NH + i - (i/NH)*NH]));
    }
    __syncthreads();
    if (tid<NH) inv[tid] = 1.f/denom[tid];
    __syncthreads();
    const float i0=inv[h0], i1=inv[h0+4], i2=inv[h0+8];
    float a0=0.f, a1=0.f, a2=0.f;
    for (int i=0;i<n;i++){
      const int e  = order[st+i];
      const int et = ei[2*EE+e], er = ei[3*EE+e];
      const bf16* vr = Vb + (size_t)(eb*NN+et)*HID;
      const bf16* erow = Eb + (size_t)er*HID;
      const float p0 = expf(L[(size_t)e*NH+h0  ])*i0;
      const float p1 = expf(L[(size_t)e*NH+h0+4])*i1;
      const float p2 = expf(L[(size_t)e*NH+h0+8])*i2;
      a0 += p0*(b2f(*(const unsigned short*)(vr+tid    ))+b2f(*(const unsigned short*)(erow+tid    )));
      a1 += p1*(b2f(*(const unsigned short*)(vr+tid+256))+b2f(*(const unsigned short*)(erow+tid+256)));
      a2 += p2*(b2f(*(const unsigned short*)(vr+tid+512))+b2f(*(const unsigned short*)(erow+tid+512)));
    }
    o[tid]=a0; o[tid+256]=a1; o[tid+512]=a2;
  }
}

// ---------------- launcher ----------------
extern "C" void kernel_launch(void* const* d_in, const int* in_sizes, int n_in,
                              void* d_out, int out_size, void* d_ws, size_t ws_size,
                              hipStream_t stream)
{
  const float* X  = (const float*)d_in[0];
  const int*   ei = (const int*)d_in[1];
  const int*   nt = (const int*)d_in[2];
  const float* W[6]; const float* bia[6];
  for (int j=0;j<6;j++){ W[j]=(const float*)d_in[3+2*j]; bia[j]=(const float*)d_in[4+2*j]; }
  const float* relm = (const float*)d_in[15];
  const float* emb  = (const float*)d_in[16];
  float* out = (float*)d_out;

  char* p = (char*)d_ws;
  bf16*  Qb = (bf16*)p;  p += (size_t)NSEG*HID*2;
  bf16*  Kb = (bf16*)p;  p += (size_t)NSEG*HID*2;
  bf16*  Vb = (bf16*)p;  p += (size_t)NSEG*HID*2;
  float* L  = (float*)p; p += (size_t)EE*NH*4;
  int* cnt      = (int*)p; p += NSEG*4;
  int* start    = (int*)p; p += NSEG*4;
  int* cursor   = (int*)p; p += NSEG*4;
  int* order    = (int*)p; p += (size_t)EE*4;
  int* cnt_blk    = (int*)p; p += NREL*NBLK*4;
  int* start_rel  = (int*)p; p += NREL*4;
  int* cnt_rel    = (int*)p; p += NREL*4;
  int* ustart     = (int*)p; p += (NREL+4)*4;
  int* order_rel  = (int*)p; p += (size_t)EE*4;
  int* origrow    = (int*)p; p += (NSEG+128)*4;
  int* meta       = (int*)p; p += 80*4;
  bf16* Xp = (bf16*)p;  p += (size_t)(NSEG+128)*HID*2;
  bf16* Wb = (bf16*)p;  p += (size_t)NOUT*HID*2;
  bf16* Mt = (bf16*)p;  p += (size_t)NREL*DH*DH*2;
  bf16* Eb = (bf16*)p;  p += (size_t)NREL*HID*2;
  float* biasAll = (float*)p; p += NOUT*4;

  partition_kernel<<<1, 1024, 0, stream>>>(nt, origrow, meta, cnt);
  prep_kernel<<<NSEG + NOUT + 2*NREL + NBLK, 256, 0, stream>>>(X, origrow,
      W[0],W[1],W[2],W[3],W[4],W[5],
      bia[0],bia[1],bia[2],bia[3],bia[4],bia[5], relm, emb, ei,
      Xp, Wb, biasAll, Mt, Eb, cnt, cnt_blk);
  gemm_kernel<<<NWG, 256, 0, stream>>>(Xp, Wb, biasAll, origrow,
      meta, Qb, Kb, Vb);

  scan_both_kernel<<<2, 1024, 0, stream>>>(cnt, start, cursor, cnt_blk,
      start_rel, cnt_rel, ustart);
  scatter_both_kernel<<<NBLK, 256, 0, stream>>>(ei, cursor, order, cnt_blk, order_rel);

  logits_mfma_kernel<<<MAXU, 256, 0, stream>>>(Qb, Kb, ei, Mt, order_rel,
      start_rel, cnt_rel, ustart, L);
  segout_kernel<<<NSEG, 256, 0, stream>>>(ei, Vb, Eb, L, start, cnt, order, out);
}

// Round 15
// 136.512 us; speedup vs baseline: 1.0052x; 1.0052x over previous
//
#include <hip/hip_runtime.h>
#include <math.h>
#include <stdint.h>

#define BB   4
#define NN   1024
#define HID  768
#define NH   12
#define DH   64
#define NREL 64
#define EE   65536
#define NSEG (BB*NN)   /* 4096 */
#define NOUT 4608      /* 6*HID stacked output features */
#define UNIT_E 32      /* edges per logits block */
#define MAXU (EE/UNIT_E + NREL)
#define NBLK 256       /* blocks in relation radix sort */
#define MAXMT 34       /* max M-tiles in partitioned GEMM */

typedef __bf16 bf16;
typedef __bf16 bf16x8 __attribute__((ext_vector_type(8)));
typedef float  f32x4  __attribute__((ext_vector_type(4)));

__device__ __forceinline__ void load_lds16(const void* g, void* l) {
  __builtin_amdgcn_global_load_lds(
      (__attribute__((address_space(1))) void*)(uintptr_t)g,
      (__attribute__((address_space(3))) void*)(uintptr_t)l, 16, 0, 0);
}

// LDS XOR swizzle (involution, moves 16B slots within each 128B window)
__device__ __forceinline__ int swz(int byte_off) {
  return byte_off ^ (((byte_off >> 7) & 7) << 4);
}

__device__ __forceinline__ float b2f(unsigned short u) {
  return __uint_as_float(((unsigned)u) << 16);
}

// ---------------- P0: partition rows by node type; zero cnt ----------------
__global__ __launch_bounds__(1024)
void partition_kernel(const int* __restrict__ nt, int* __restrict__ origrow,
                      int* __restrict__ meta, int* __restrict__ cnt){
  __shared__ int sums[1024];
  __shared__ int ntot;
  const int t = threadIdx.x;
  int tk[4]; int c = 0;
  #pragma unroll
  for (int i=0;i<4;i++){ tk[i] = (nt[t*4+i]==0); c += tk[i]; cnt[t*4+i] = 0; }
  sums[t]=c; __syncthreads();
  for (int off=1; off<1024; off<<=1){
    const int v = (t>=off) ? sums[t-off] : 0;
    __syncthreads();
    sums[t]+=v;
    __syncthreads();
  }
  if (t==1023) ntot = sums[1023];
  __syncthreads();
  const int excl = sums[t]-c;
  int tokpos = excl, kbpos = ntot + (4*t - excl);
  #pragma unroll
  for (int i=0;i<4;i++){
    if (tk[i]) origrow[tokpos++] = t*4+i;
    else       origrow[kbpos++]  = t*4+i;
  }
  if (t==0){
    const int ntok = ntot, nkb = NSEG - ntok;
    const int tt = (ntok+127)>>7, ktt = (nkb+127)>>7;
    meta[0]=ntok; meta[1]=tt+ktt;
    for (int m=0;m<tt+ktt;m++){
      meta[2+m]  = (m<tt) ? m*128 : ntok + (m-tt)*128;
      meta[40+m] = (m<tt) ? 1 : 0;
    }
  }
}

// ---------------- P1: fused converts (X-gather, W stack, M^T, emb) + histograms ----
__global__ __launch_bounds__(256)
void prep_kernel(const float* __restrict__ X, const int* __restrict__ origrow,
                 const float* __restrict__ W0, const float* __restrict__ W1,
                 const float* __restrict__ W2, const float* __restrict__ W3,
                 const float* __restrict__ W4, const float* __restrict__ W5,
                 const float* __restrict__ b0, const float* __restrict__ b1,
                 const float* __restrict__ b2, const float* __restrict__ b3,
                 const float* __restrict__ b4, const float* __restrict__ b5,
                 const float* __restrict__ relm, const float* __restrict__ emb,
                 const int* __restrict__ ei,
                 bf16* __restrict__ Xp, bf16* __restrict__ Wb,
                 float* __restrict__ biasAll, bf16* __restrict__ Mt,
                 bf16* __restrict__ Eb, int* __restrict__ cnt,
                 int* __restrict__ cnt_blk){
  __shared__ int lc[NREL];
  const int blk = blockIdx.x, tid = threadIdx.x;
  if (blk < NSEG) {
    if (tid < 192) {
      const int orig = origrow[blk];
      float4 v = *reinterpret_cast<const float4*>(X + (size_t)orig*HID + tid*4);
      bf16 o[4] = {(bf16)v.x,(bf16)v.y,(bf16)v.z,(bf16)v.w};
      *reinterpret_cast<uint64_t*>(Xp + (size_t)blk*HID + tid*4) = *reinterpret_cast<uint64_t*>(o);
    }
  } else if (blk < NSEG + NOUT) {
    const int r = blk - NSEG;
    const int j = r / HID;
    const int o = r - j * HID;
    const float* Wj; const float* bj;
    if      (j==0){Wj=W0;bj=b0;} else if(j==1){Wj=W1;bj=b1;}
    else if (j==2){Wj=W2;bj=b2;} else if(j==3){Wj=W3;bj=b3;}
    else if (j==4){Wj=W4;bj=b4;} else            {Wj=W5;bj=b5;}
    if (tid < 192) {
      float4 v = *reinterpret_cast<const float4*>(Wj + (size_t)o*HID + tid*4);
      bf16 ob[4] = {(bf16)v.x,(bf16)v.y,(bf16)v.z,(bf16)v.w};
      *reinterpret_cast<uint64_t*>(Wb + (size_t)r*HID + tid*4) = *reinterpret_cast<uint64_t*>(ob);
    }
    if (tid == 0) biasAll[r] = bj[o];
  } else if (blk < NSEG + NOUT + NREL) {
    const int r = blk - NSEG - NOUT;
    const float* M = relm + (size_t)r * DH * DH;
    bf16* o = Mt + (size_t)r * DH * DH;
    for (int i = tid; i < DH * DH; i += 256) {
      const int d = i >> 6, f = i & 63;
      o[f * DH + d] = (bf16)M[i];
    }
  } else if (blk < NSEG + NOUT + 2*NREL) {
    const int r = blk - NSEG - NOUT - NREL;
    const float* src = emb + (size_t)r * HID;
    bf16* dst = Eb + (size_t)r * HID;
    for (int c = tid; c < HID; c += 256) dst[c] = (bf16)src[c];
  } else {
    // fused histograms: seg (global atomics) + rel (LDS -> cnt_blk)
    const int blk2 = blk - (NSEG + NOUT + 2*NREL);
    if (tid < NREL) lc[tid] = 0;
    __syncthreads();
    const int e = blk2*256 + tid;
    atomicAdd(&cnt[ei[e]*NN + ei[EE+e]], 1);
    atomicAdd(&lc[ei[3*EE+e]], 1);
    __syncthreads();
    if (tid < NREL) cnt_blk[tid*NBLK + blk2] = lc[tid];
  }
}

// ---------------- K1: type-partitioned bf16 MFMA GEMM, 128x256 tile ----------------
// 4 waves of 64x128 (af[4] reused x8, bfr[8] reused x4 -> LDS bytes/MFMA 768->563).
// 3-buffer LDS pipeline, counted vmcnt, one raw barrier/iter, XCD-chunked m-major grid.
#define BM 128
#define BN 256
#define BK 32
#define NT (HID/BK)   /* 24 K-iterations */
#define NCT (2304/BN) /* 9 col tiles */
#define NWG (MAXMT*NCT) /* 306 */

__global__ __launch_bounds__(256, 2)
void gemm_kernel(const bf16* __restrict__ A, const bf16* __restrict__ Bw,
                 const float* __restrict__ biasAll, const int* __restrict__ origrow,
                 const int* __restrict__ meta,
                 bf16* __restrict__ Qb, bf16* __restrict__ Kb, bf16* __restrict__ Vb)
{
  __shared__ bf16 As[3][BM * BK];   // 3 x 8 KB
  __shared__ bf16 Bs[3][BN * BK];   // 3 x 16 KB

  // m204 bijective XCD chunking: q=306/8=38, r=306%8=2
  const int orig = blockIdx.x;
  const int xcd  = orig & 7;
  const int wg   = (xcd < 2 ? xcd * 39 : 2 * 39 + (xcd - 2) * 38) + (orig >> 3);
  const int mt   = wg / NCT;        // m-major: consecutive wg share mt (A-local per XCD)
  const int ctt  = wg - mt * NCT;

  const int ntok = meta[0], nmt = meta[1];
  if (mt >= nmt) return;
  const int base  = meta[2+mt];
  const int istok = meta[40+mt];

  const int tid  = threadIdx.x;
  const int lane = tid & 63;
  const int w    = tid >> 6;
  const int wrow = w >> 1, wcol = w & 1;   // 2x2 waves; wave tile 64x128
  const int ct_local = ctt * BN;           // 0..2048; 256-tile never straddles Q/K/V (768=3*256)
  const int brow0 = (istok ? 0 : 2304) + ct_local;

  f32x4 acc[4][8];
  #pragma unroll
  for (int mi=0;mi<4;mi++)
    #pragma unroll
    for (int ni=0;ni<8;ni++) acc[mi][ni] = (f32x4){0.f,0.f,0.f,0.f};

  const char* Ab = (const char*)A;
  const char* Bb = (const char*)Bw;

  // staging geometry: A = 512 slots (2/thread), B = 1024 slots (4/thread)
  int rowgA[2], inrowgA[2], PgA[2];
  #pragma unroll
  for (int i = 0; i < 2; ++i) {
    const int P = (i * 256 + tid) * 16;
    const int L = swz(P);
    PgA[i] = P; rowgA[i] = L >> 6; inrowgA[i] = L & 63;
  }
  int rowgB[4], inrowgB[4], PgB[4];
  #pragma unroll
  for (int i = 0; i < 4; ++i) {
    const int P = (i * 256 + tid) * 16;
    const int L = swz(P);
    PgB[i] = P; rowgB[i] = L >> 6; inrowgB[i] = L & 63;
  }

  #define STAGE(kt, b)                                                              \
    { _Pragma("unroll")                                                             \
      for (int i = 0; i < 2; ++i)                                                   \
        load_lds16(Ab + ((size_t)(base  + rowgA[i]) * HID + (kt) * BK) * 2 + inrowgA[i], \
                   (char*)As[b] + PgA[i]);                                          \
      _Pragma("unroll")                                                             \
      for (int i = 0; i < 4; ++i)                                                   \
        load_lds16(Bb + ((size_t)(brow0 + rowgB[i]) * HID + (kt) * BK) * 2 + inrowgB[i], \
                   (char*)Bs[b] + PgB[i]); }

  STAGE(0, 0);
  STAGE(1, 1);

  for (int kt = 0; kt < NT; ++kt) {
    if (kt < NT - 1) asm volatile("s_waitcnt vmcnt(6)" ::: "memory");
    else             asm volatile("s_waitcnt vmcnt(0)" ::: "memory");
    __builtin_amdgcn_s_barrier();
    if (kt + 2 < NT) { STAGE(kt + 2, (kt + 2) % 3); }

    const char* Asb = (const char*)As[kt % 3];
    const char* Bsb = (const char*)Bs[kt % 3];
    bf16x8 af[4], bfr[8];
    #pragma unroll
    for (int mi = 0; mi < 4; ++mi) {
      const int r = wrow * 64 + mi * 16 + (lane & 15);
      const int L = r * 64 + (lane >> 4) * 16;
      af[mi] = *reinterpret_cast<const bf16x8*>(Asb + swz(L));
    }
    #pragma unroll
    for (int ni = 0; ni < 8; ++ni) {
      const int r = wcol * 128 + ni * 16 + (lane & 15);
      const int L = r * 64 + (lane >> 4) * 16;
      bfr[ni] = *reinterpret_cast<const bf16x8*>(Bsb + swz(L));
    }
    #pragma unroll
    for (int mi = 0; mi < 4; ++mi)
      #pragma unroll
      for (int ni = 0; ni < 8; ++ni)
        acc[mi][ni] = __builtin_amdgcn_mfma_f32_16x16x32_bf16(af[mi], bfr[ni], acc[mi][ni], 0, 0, 0);
  }

  const int j3 = ct_local / HID;
  const int o0 = ct_local - j3 * HID;
  const int rowLim = istok ? ntok : NSEG;
  const int bidx0 = (istok ? j3 : j3 + 3) * HID + o0;
  #pragma unroll
  for (int mi = 0; mi < 4; ++mi) {
    #pragma unroll
    for (int i = 0; i < 4; ++i) {
      const int rr = base + wrow * 64 + mi * 16 + (lane >> 4) * 4 + i;
      if (rr < rowLim) {
        const int orig2 = origrow[rr];
        #pragma unroll
        for (int ni = 0; ni < 8; ++ni) {
          const int cg = wcol * 128 + ni * 16 + (lane & 15);
          const float val = acc[mi][ni][i] + biasAll[bidx0 + cg];
          if (j3 == 2)      Vb[(size_t)orig2 * HID + o0 + cg] = (bf16)val;
          else if (j3 == 0) Qb[(size_t)orig2 * HID + o0 + cg] = (bf16)val;
          else              Kb[(size_t)orig2 * HID + o0 + cg] = (bf16)val;
        }
      }
    }
  }
}

// ---------------- fused scans ----------------
__global__ __launch_bounds__(1024)
void scan_both_kernel(const int* __restrict__ cnt, int* __restrict__ start,
                      int* __restrict__ cursor, int* __restrict__ cnt_blk,
                      int* __restrict__ start_rel, int* __restrict__ cnt_rel,
                      int* __restrict__ ustart){
  __shared__ int sums[1024];
  const int t = threadIdx.x;
  if (blockIdx.x == 0) {
    const int c0=cnt[t*4], c1=cnt[t*4+1], c2=cnt[t*4+2], c3=cnt[t*4+3];
    const int s = c0+c1+c2+c3;
    sums[t]=s; __syncthreads();
    for (int off=1; off<1024; off<<=1){
      const int v = (t>=off) ? sums[t-off] : 0;
      __syncthreads();
      sums[t]+=v;
      __syncthreads();
    }
    const int excl = sums[t]-s;
    const int o0=excl, o1=o0+c0, o2=o1+c1, o3=o2+c2;
    start[t*4]=o0;  start[t*4+1]=o1;  start[t*4+2]=o2;  start[t*4+3]=o3;
    cursor[t*4]=o0; cursor[t*4+1]=o1; cursor[t*4+2]=o2; cursor[t*4+3]=o3;
  } else {
    int v[16]; int s = 0;
    #pragma unroll
    for (int i=0;i<16;i++){ v[i] = cnt_blk[t*16+i]; s += v[i]; }
    sums[t] = s; __syncthreads();
    for (int off=1; off<1024; off<<=1){
      const int x = (t>=off) ? sums[t-off] : 0;
      __syncthreads();
      sums[t] += x;
      __syncthreads();
    }
    int run = sums[t] - s;
    #pragma unroll
    for (int i=0;i<16;i++){ const int c = v[i]; cnt_blk[t*16+i] = run; run += c; }
    __syncthreads();
    if (t < NREL) {
      const int st  = cnt_blk[t*NBLK];
      const int nxt = (t == NREL-1) ? EE : cnt_blk[(t+1)*NBLK];
      const int c   = nxt - st;
      start_rel[t] = st;
      cnt_rel[t]   = c;
      const int units = (c + UNIT_E - 1) / UNIT_E;
      int su = units;
      #pragma unroll
      for (int off=1; off<64; off<<=1) {
        const int vu = __shfl_up(su, off);
        if (t >= off) su += vu;
      }
      ustart[t] = su - units;
      if (t == NREL-1) ustart[NREL] = su;
    }
  }
}

// ---------------- fused scatters ----------------
__global__ __launch_bounds__(256)
void scatter_both_kernel(const int* __restrict__ ei, int* __restrict__ cursor,
                         int* __restrict__ order, const int* __restrict__ base_blk,
                         int* __restrict__ order_rel){
  __shared__ int lc[NREL];
  const int tid = threadIdx.x, blk = blockIdx.x;
  if (tid < NREL) lc[tid] = 0;
  __syncthreads();
  const int e = blk*256 + tid;
  const int seg = ei[e]*NN + ei[EE+e];
  order[atomicAdd(&cursor[seg], 1)] = e;
  const int r = ei[3*EE + e];
  const int rank = atomicAdd(&lc[r], 1);
  order_rel[base_blk[r*NBLK + blk] + rank] = e;
}

// ---------------- K2: relation-batched MFMA logits, 32 edges/block, pipelined ----
// wave handles 8 edges = 96 (edge,head) rows = 6 tiles of 16
__global__ __launch_bounds__(256)
void logits_mfma_kernel(const bf16* __restrict__ Qb, const bf16* __restrict__ Kb,
                        const int* __restrict__ ei, const bf16* __restrict__ Mt,
                        const int* __restrict__ order_rel, const int* __restrict__ start_rel,
                        const int* __restrict__ cnt_rel, const int* __restrict__ ustart,
                        float* __restrict__ L)
{
  __shared__ int qoff[UNIT_E], koff[UNIT_E], eidx[UNIT_E];
  __shared__ int us[NREL+1];
  __shared__ int relsh;
  const int tid = threadIdx.x;
  const int u = blockIdx.x;
  if (tid < NREL+1) us[tid] = ustart[tid];
  __syncthreads();
  if (u >= us[NREL]) return;
  if (tid < NREL && us[tid] <= u && u < us[tid+1]) relsh = tid;
  __syncthreads();
  const int r = relsh;
  const int lu = u - us[r];
  const int ebase = start_rel[r] + lu * UNIT_E;
  const int nvalid = min(UNIT_E, cnt_rel[r] - lu * UNIT_E);
  if (tid < UNIT_E) {
    const int epos = ebase + (tid < nvalid ? tid : 0);
    const int e = order_rel[epos];
    eidx[tid] = (tid < nvalid) ? e : -1;
    const int eb = ei[e], eh = ei[EE+e], et = ei[2*EE+e];
    qoff[tid] = (eb*NN + eh) * HID;
    koff[tid] = (eb*NN + et) * HID;
  }
  __syncthreads();

  const int w = tid >> 6, lane = tid & 63;
  const int l15 = lane & 15, lg = lane >> 4;
  const bf16* Mr = Mt + (size_t)r * DH * DH;
  bf16x8 bfr[4][2];
  #pragma unroll
  for (int ni = 0; ni < 4; ++ni)
    #pragma unroll
    for (int kk = 0; kk < 2; ++kk)
      bfr[ni][kk] = *reinterpret_cast<const bf16x8*>(
          Mr + (ni*16 + l15) * DH + kk*32 + lg*8);

  #define LOADQ(mt, a0, a1)                                              \
    { const int lr = (mt)*16 + l15;                                      \
      const int el = lr / 12, hh = lr - el*12;                           \
      const int qo = qoff[w*8 + el] + hh*64 + lg*8;                      \
      a0 = *reinterpret_cast<const bf16x8*>(Qb + qo);                    \
      a1 = *reinterpret_cast<const bf16x8*>(Qb + qo + 32); }

  #define LOADK(mt, kr)                                                  \
    { _Pragma("unroll")                                                  \
      for (int i = 0; i < 4; ++i) {                                      \
        const int lr2 = (mt)*16 + lg*4 + i;                              \
        const int el2 = lr2 / 12, h2 = lr2 - el2*12;                     \
        const int ko = koff[w*8 + el2] + h2*64 + l15;                    \
        _Pragma("unroll")                                                \
        for (int ni = 0; ni < 4; ++ni)                                   \
          kr[i*4+ni] = *reinterpret_cast<const unsigned short*>(Kb + ko + ni*16); } }

  #define COMPUTE(mt, a0, a1, kr)                                        \
    { f32x4 acc_[4];                                                     \
      _Pragma("unroll")                                                  \
      for (int ni = 0; ni < 4; ++ni) {                                   \
        acc_[ni] = (f32x4){0.f,0.f,0.f,0.f};                             \
        acc_[ni] = __builtin_amdgcn_mfma_f32_16x16x32_bf16(a0, bfr[ni][0], acc_[ni], 0, 0, 0); \
        acc_[ni] = __builtin_amdgcn_mfma_f32_16x16x32_bf16(a1, bfr[ni][1], acc_[ni], 0, 0, 0); \
      }                                                                  \
      _Pragma("unroll")                                                  \
      for (int i = 0; i < 4; ++i) {                                      \
        const int lr2 = (mt)*16 + lg*4 + i;                              \
        const int el2 = lr2 / 12, h2 = lr2 - el2*12;                     \
        float p = acc_[0][i]*b2f(kr[i*4+0]) + acc_[1][i]*b2f(kr[i*4+1])  \
                + acc_[2][i]*b2f(kr[i*4+2]) + acc_[3][i]*b2f(kr[i*4+3]); \
        p += __shfl_xor(p, 1); p += __shfl_xor(p, 2);                    \
        p += __shfl_xor(p, 4); p += __shfl_xor(p, 8);                    \
        if (l15 == 0) {                                                  \
          const int e = eidx[w*8 + el2];                                 \
          if (e >= 0) L[(size_t)e*NH + h2] = p * 0.125f;                 \
        } } }

  bf16x8 a0A, a1A, a0B, a1B;
  unsigned short krA[16], krB[16];
  LOADQ(0, a0A, a1A); LOADK(0, krA);
  #pragma unroll
  for (int mt = 0; mt < 6; mt += 2) {
    LOADQ(mt+1, a0B, a1B); LOADK(mt+1, krB);
    COMPUTE(mt, a0A, a1A, krA);
    if (mt + 2 < 6) { LOADQ(mt+2, a0A, a1A); LOADK(mt+2, krA); }
    COMPUTE(mt+1, a0B, a1B, krB);
  }
  #undef LOADQ
  #undef LOADK
  #undef COMPUTE
}

// ---------------- K4: per-segment softmax + weighted V scatter-sum ----------------
#define SEGCAP 128
__global__ __launch_bounds__(256)
void segout_kernel(const int* __restrict__ ei, const bf16* __restrict__ Vb,
                   const bf16* __restrict__ Eb, const float* __restrict__ L,
                   const int* __restrict__ start, const int* __restrict__ cnt,
                   const int* __restrict__ order, float* __restrict__ out)
{
  const int s = blockIdx.x, tid = threadIdx.x;
  float* o = out + (size_t)s*HID;
  const int n = cnt[s];
  if (n==0){ o[tid]=0.f; o[tid+256]=0.f; o[tid+512]=0.f; return; }

  __shared__ float denom[NH];
  __shared__ float inv[NH];
  const int st = start[s];
  const int eb = s >> 10;
  const int h0 = tid >> 6;

  if (tid<NH) denom[tid]=0.f;

  if (n <= SEGCAP) {
    __shared__ float pr[SEGCAP*NH];
    __shared__ int voffs[SEGCAP];
    __shared__ int eoffs[SEGCAP];
    if (tid < n) {
      const int e = order[st + tid];
      voffs[tid] = (eb*NN + ei[2*EE+e]) * HID;
      eoffs[tid] = ei[3*EE+e] * HID;
    }
    __syncthreads();
    for (int idx=tid; idx<n*NH; idx+=256){
      const int e = order[st + idx/NH];
      const float v = expf(L[(size_t)e*NH + idx - (idx/NH)*NH]);
      pr[idx] = v;
      atomicAdd(&denom[idx - (idx/NH)*NH], v);
    }
    __syncthreads();
    if (tid<NH) inv[tid] = 1.f/denom[tid];
    __syncthreads();
    const float i0=inv[h0], i1=inv[h0+4], i2=inv[h0+8];
    float a0=0.f, a1=0.f, a2=0.f;
    float b0_=0.f, b1_=0.f, b2_=0.f;
    #define EDGE_ACC(ii, A0, A1, A2)                                                     \
      { const bf16* vr = Vb + voffs[ii];                                                 \
        const bf16* er = Eb + eoffs[ii];                                                 \
        const float p0 = pr[(ii)*NH+h0  ]*i0;                                            \
        const float p1 = pr[(ii)*NH+h0+4]*i1;                                            \
        const float p2 = pr[(ii)*NH+h0+8]*i2;                                            \
        A0 += p0*(b2f(*(const unsigned short*)(vr+tid    ))+b2f(*(const unsigned short*)(er+tid    ))); \
        A1 += p1*(b2f(*(const unsigned short*)(vr+tid+256))+b2f(*(const unsigned short*)(er+tid+256))); \
        A2 += p2*(b2f(*(const unsigned short*)(vr+tid+512))+b2f(*(const unsigned short*)(er+tid+512))); }
    int i = 0;
    for (; i+3<n; i+=4){
      EDGE_ACC(i,   a0,  a1,  a2);
      EDGE_ACC(i+1, b0_, b1_, b2_);
      EDGE_ACC(i+2, a0,  a1,  a2);
      EDGE_ACC(i+3, b0_, b1_, b2_);
    }
    for (; i<n; ++i){
      EDGE_ACC(i, a0, a1, a2);
    }
    #undef EDGE_ACC
    o[tid]=a0+b0_; o[tid+256]=a1+b1_; o[tid+512]=a2+b2_;
  } else {
    __syncthreads();
    for (int i=tid; i<n*NH; i+=256){
      const int e = order[st + i/NH];
      atomicAdd(&denom[i - (i/NH)*NH], expf(L[(size_t)e*NH + i - (i/NH)*NH]));
    }
    __syncthreads();
    if (tid<NH) inv[tid] = 1.f/denom[tid];
    __syncthreads();
    const float i0=inv[h0], i1=inv[h0+4], i2=inv[h0+8];
    float a0=0.f, a1=0.f, a2=0.f;
    for (int i=0;i<n;i++){
      const int e  = order[st+i];
      const int et = ei[2*EE+e], er = ei[3*EE+e];
      const bf16* vr = Vb + (size_t)(eb*NN+et)*HID;
      const bf16* erow = Eb + (size_t)er*HID;
      const float p0 = expf(L[(size_t)e*NH+h0  ])*i0;
      const float p1 = expf(L[(size_t)e*NH+h0+4])*i1;
      const float p2 = expf(L[(size_t)e*NH+h0+8])*i2;
      a0 += p0*(b2f(*(const unsigned short*)(vr+tid    ))+b2f(*(const unsigned short*)(erow+tid    )));
      a1 += p1*(b2f(*(const unsigned short*)(vr+tid+256))+b2f(*(const unsigned short*)(erow+tid+256)));
      a2 += p2*(b2f(*(const unsigned short*)(vr+tid+512))+b2f(*(const unsigned short*)(erow+tid+512)));
    }
    o[tid]=a0; o[tid+256]=a1; o[tid+512]=a2;
  }
}

// ---------------- launcher ----------------
extern "C" void kernel_launch(void* const* d_in, const int* in_sizes, int n_in,
                              void* d_out, int out_size, void* d_ws, size_t ws_size,
                              hipStream_t stream)
{
  const float* X  = (const float*)d_in[0];
  const int*   ei = (const int*)d_in[1];
  const int*   nt = (const int*)d_in[2];
  const float* W[6]; const float* bia[6];
  for (int j=0;j<6;j++){ W[j]=(const float*)d_in[3+2*j]; bia[j]=(const float*)d_in[4+2*j]; }
  const float* relm = (const float*)d_in[15];
  const float* emb  = (const float*)d_in[16];
  float* out = (float*)d_out;

  char* p = (char*)d_ws;
  bf16*  Qb = (bf16*)p;  p += (size_t)NSEG*HID*2;
  bf16*  Kb = (bf16*)p;  p += (size_t)NSEG*HID*2;
  bf16*  Vb = (bf16*)p;  p += (size_t)NSEG*HID*2;
  float* L  = (float*)p; p += (size_t)EE*NH*4;
  int* cnt      = (int*)p; p += NSEG*4;
  int* start    = (int*)p; p += NSEG*4;
  int* cursor   = (int*)p; p += NSEG*4;
  int* order    = (int*)p; p += (size_t)EE*4;
  int* cnt_blk    = (int*)p; p += NREL*NBLK*4;
  int* start_rel  = (int*)p; p += NREL*4;
  int* cnt_rel    = (int*)p; p += NREL*4;
  int* ustart     = (int*)p; p += (NREL+4)*4;
  int* order_rel  = (int*)p; p += (size_t)EE*4;
  int* origrow    = (int*)p; p += (NSEG+128)*4;
  int* meta       = (int*)p; p += 80*4;
  bf16* Xp = (bf16*)p;  p += (size_t)(NSEG+128)*HID*2;
  bf16* Wb = (bf16*)p;  p += (size_t)NOUT*HID*2;
  bf16* Mt = (bf16*)p;  p += (size_t)NREL*DH*DH*2;
  bf16* Eb = (bf16*)p;  p += (size_t)NREL*HID*2;
  float* biasAll = (float*)p; p += NOUT*4;

  partition_kernel<<<1, 1024, 0, stream>>>(nt, origrow, meta, cnt);
  prep_kernel<<<NSEG + NOUT + 2*NREL + NBLK, 256, 0, stream>>>(X, origrow,
      W[0],W[1],W[2],W[3],W[4],W[5],
      bia[0],bia[1],bia[2],bia[3],bia[4],bia[5], relm, emb, ei,
      Xp, Wb, biasAll, Mt, Eb, cnt, cnt_blk);
  gemm_kernel<<<NWG, 256, 0, stream>>>(Xp, Wb, biasAll, origrow,
      meta, Qb, Kb, Vb);

  scan_both_kernel<<<2, 1024, 0, stream>>>(cnt, start, cursor, cnt_blk,
      start_rel, cnt_rel, ustart);
  scatter_both_kernel<<<NBLK, 256, 0, stream>>>(ei, cursor, order, cnt_blk, order_rel);

  logits_mfma_kernel<<<MAXU, 256, 0, stream>>>(Qb, Kb, ei, Mt, order_rel,
      start_rel, cnt_rel, ustart, L);
  segout_kernel<<<NSEG, 256, 0, stream>>>(ei, Vb, Eb, L, start, cnt, order, out);
}